// Round 1
// baseline (390.644 us; speedup 1.0000x reference)
//
#include <hip/hip_runtime.h>
#include <math.h>
#include <float.h>

#define DDIM 1024   // D
#define PDIM 32     // pattern_dim
#define NPAT 256    // n_patterns
#define TOPK 4
#define BLOCK 256
#define GT   16     // tokens per tile
#define DCH  256    // d-chunk per block
#define NCH  4      // d-chunks (DDIM/DCH)
#define RTPB 4      // tokens per route block (one per wave)

// ---------------------------------------------------------------------------
// K0 (R8): routing, one WAVE per token, 4 tokens/block, 512 blocks.
// Lane l holds x[tok][d] for d in {i*256 + l*4 ..+3, i=0..3} (16 floats) and
// accumulates partial h for ALL 32 pattern-dims in registers. Transpose-
// reduce via LDS P[l][pp] (row pad 33 -> banks (l+pp)%32, 2-way max = free).
// Then in-wave sim vs 256 keys + top-4 butterfly argmax (tie -> lower index)
// + softmax (logic verbatim from R7 phase 2, which validated).
__global__ __launch_bounds__(BLOCK) void route_kernel(
    const float* __restrict__ x,
    const float* __restrict__ hasher_w,   // [PDIM, DDIM]
    const float* __restrict__ keys,       // [NPAT, PDIM]
    int*   __restrict__ tki,              // [ntok, TOPK]
    float* __restrict__ tkw,              // [ntok, TOPK]
    int ntok)
{
    __shared__ float P_s[RTPB][64 * 33];  // 33.8 KB transpose scratch
    __shared__ float h_s[RTPB][32];

    const int tid  = threadIdx.x;
    const int wv   = tid >> 6;            // wave 0..3 = local token
    const int lane = tid & 63;
    const int tok  = min(blockIdx.x * RTPB + wv, ntok - 1);  // clamp (dup-write benign)

    // ---- x row into registers (coalesced float4)
    const float4* xrow = (const float4*)(x + (size_t)tok * DDIM);
    float4 xr[4];
    #pragma unroll
    for (int i = 0; i < 4; ++i) xr[i] = xrow[i * 64 + lane];

    // ---- per-lane partial h[pp] over this lane's 16 d's
    float part[PDIM];
    #pragma unroll
    for (int pp = 0; pp < PDIM; ++pp) {
        const float4* wrow = (const float4*)(hasher_w + (size_t)pp * DDIM);
        float a = 0.f;
        #pragma unroll
        for (int i = 0; i < 4; ++i) {
            const float4 w4 = wrow[i * 64 + lane];
            a = fmaf(xr[i].x, w4.x, a); a = fmaf(xr[i].y, w4.y, a);
            a = fmaf(xr[i].z, w4.z, a); a = fmaf(xr[i].w, w4.w, a);
        }
        part[pp] = a;
    }

    // ---- transpose-reduce: P[l][pp] -> h[pp]
    float* P = P_s[wv];
    #pragma unroll
    for (int pp = 0; pp < PDIM; ++pp) P[lane * 33 + pp] = part[pp];
    __syncthreads();

    {
        const int pp = lane & 31, half = lane >> 5;
        float hsum = 0.f;
        #pragma unroll 8
        for (int i = 0; i < 32; ++i)
            hsum += P[(half * 32 + i) * 33 + pp];
        hsum += __shfl_xor(hsum, 32, 64);
        if (half == 0) h_s[wv][pp] = hsum;
    }
    __syncthreads();

    // ---- sim + top4 + softmax (in-wave; verbatim logic from R7 phase 2)
    float4 h4[8];
    #pragma unroll
    for (int i = 0; i < 8; ++i) h4[i] = *(const float4*)&h_s[wv][i * 4];

    float sc0, sc1, sc2, sc3;
    {
        float sv[4];
        #pragma unroll
        for (int c = 0; c < 4; ++c) {
            const float4* kr = (const float4*)(keys + (size_t)(c * 64 + lane) * PDIM);
            float a = 0.f;
            #pragma unroll
            for (int i = 0; i < 8; ++i) {
                const float4 k4 = kr[i];
                a = fmaf(k4.x, h4[i].x, a); a = fmaf(k4.y, h4[i].y, a);
                a = fmaf(k4.z, h4[i].z, a); a = fmaf(k4.w, h4[i].w, a);
            }
            sv[c] = a;
        }
        sc0 = sv[0]; sc1 = sv[1]; sc2 = sv[2]; sc3 = sv[3];
    }

    float wval[TOPK]; int widx[TOPK];
    #pragma unroll
    for (int r = 0; r < TOPK; ++r) {
        float bv = sc0; int bc = 0;
        if (sc1 > bv) { bv = sc1; bc = 1; }
        if (sc2 > bv) { bv = sc2; bc = 2; }
        if (sc3 > bv) { bv = sc3; bc = 3; }
        int bidx = bc * 64 + lane;
        #pragma unroll
        for (int off = 1; off < 64; off <<= 1) {
            const float ov = __shfl_xor(bv, off, 64);
            const int   oi = __shfl_xor(bidx, off, 64);
            if (ov > bv || (ov == bv && oi < bidx)) { bv = ov; bidx = oi; }
        }
        wval[r] = bv; widx[r] = bidx;
        if ((bidx & 63) == lane) {
            const int c = bidx >> 6;
            if (c == 0) sc0 = -FLT_MAX;
            else if (c == 1) sc1 = -FLT_MAX;
            else if (c == 2) sc2 = -FLT_MAX;
            else sc3 = -FLT_MAX;
        }
    }

    if (lane == 0) {
        float m = wval[0];
        #pragma unroll
        for (int k = 1; k < TOPK; ++k) m = fmaxf(m, wval[k]);
        float s = 0.f, e[TOPK];
        #pragma unroll
        for (int k = 0; k < TOPK; ++k) { e[k] = expf(wval[k] - m); s += e[k]; }
        #pragma unroll
        for (int k = 0; k < TOPK; ++k) {
            tki[tok * TOPK + k] = widx[k];
            tkw[tok * TOPK + k] = e[k] / s;
        }
    }
}

// ---------------------------------------------------------------------------
// K1: count (from tki, in LDS) + scan + CSR fill, single block (R7-verified).
__global__ __launch_bounds__(NPAT) void scanfill_kernel(
    const int* __restrict__ tki, const float* __restrict__ tkw,
    const float* __restrict__ scale_p,
    int* __restrict__ offs,
    int* __restrict__ etok, float* __restrict__ ew, int* __restrict__ slotof,
    int nent)
{
    __shared__ int s[NPAT];
    __shared__ int cur[NPAT];
    const int tid = threadIdx.x;

    cur[tid] = 0;
    __syncthreads();
    for (int e = tid; e < nent; e += NPAT) atomicAdd(&cur[tki[e]], 1);
    __syncthreads();

    const int v = cur[tid];
    s[tid] = v;
    __syncthreads();
    for (int off = 1; off < NPAT; off <<= 1) {
        int t = 0;
        if (tid >= off) t = s[tid - off];
        __syncthreads();
        s[tid] += t;
        __syncthreads();
    }
    const int incl = s[tid];
    offs[tid + 1] = incl;
    if (tid == 0) offs[0] = 0;
    cur[tid] = incl - v;
    __syncthreads();

    const float sc = scale_p[0];
    for (int e = tid; e < nent; e += NPAT) {
        const int p = tki[e];
        const int slot = atomicAdd(&cur[p], 1);
        etok[slot] = e >> 2;
        ew[slot]   = tkw[e] * sc;
        slotof[e]  = slot;
    }
}

// ---------------------------------------------------------------------------
// K2 (R9): down-projection, d-split. NO LDS weight staging: the weight
// fragments v0..v3 are register-reused across all GT=16 tokens, so we read
// vd directly from global (L1 holds the 32 KB panel; L2 amplification is
// only ~2x = 64 MB total, ~2 us at L2 BW). LDS drops 58->25 KB, the bulk
// staging barrier disappears, and occupancy doubles -> more loads in flight.
__global__ __launch_bounds__(BLOCK, 4) void proj_kernel(
    const float* __restrict__ x,
    const float* __restrict__ vd,          // [NPAT, DDIM, PDIM]
    const int* __restrict__ offs,
    const int* __restrict__ etok,
    float* __restrict__ part,              // [NCH][nent+1][PDIM]
    int nent)
{
    __shared__ float x_s[GT * DCH];        // 16 KB
    __shared__ float red[4][8][68];        // 8.7 KB
    __shared__ int   gt[GT];
    __shared__ int   gs[GT];

    const int p   = blockIdx.x >> 2;
    const int c   = blockIdx.x & 3;
    const int tid = threadIdx.x;
    const int off0 = offs[p];
    const int n    = offs[p + 1] - off0;
    if (n == 0) return;

    const float* vdp = vd + (size_t)p * DDIM * PDIM + (size_t)c * DCH * PDIM;

    const int pp4 = tid & 7;
    const int seg = tid >> 3;
    float* partc = part + (size_t)c * (size_t)(nent + 1) * PDIM;

    for (int t0 = 0; t0 < n; t0 += GT) {
        const int gv = min(GT, n - t0);
        if (tid < GT) {
            if (tid < gv) { gt[tid] = etok[off0 + t0 + tid]; gs[tid] = off0 + t0 + tid; }
            else          { gt[tid] = etok[off0];            gs[tid] = nent; }
        }
        __syncthreads();

        #pragma unroll
        for (int k = 0; k < 4; ++k) {
            const int q  = k * 256 + tid;
            const int g  = q >> 6, fi = q & 63;
            ((float4*)x_s)[g * 64 + fi] =
                *(const float4*)(x + (size_t)gt[g] * DDIM + c * DCH + fi * 4);
        }
        __syncthreads();

        float4 acc[GT];
        #pragma unroll
        for (int g = 0; g < GT; ++g) acc[g] = make_float4(0.f, 0.f, 0.f, 0.f);

        #pragma unroll
        for (int i4 = 0; i4 < 2; ++i4) {
            const int d0 = seg * 8 + i4 * 4;
            const float* vdr = vdp + (size_t)d0 * PDIM + pp4 * 4;
            const float4 v0 = *(const float4*)(vdr + 0 * PDIM);
            const float4 v1 = *(const float4*)(vdr + 1 * PDIM);
            const float4 v2 = *(const float4*)(vdr + 2 * PDIM);
            const float4 v3 = *(const float4*)(vdr + 3 * PDIM);
            #pragma unroll
            for (int g = 0; g < GT; ++g) {
                const float4 xg = *(const float4*)&x_s[g * DCH + d0];
                acc[g].x = fmaf(xg.x, v0.x, acc[g].x);
                acc[g].y = fmaf(xg.x, v0.y, acc[g].y);
                acc[g].z = fmaf(xg.x, v0.z, acc[g].z);
                acc[g].w = fmaf(xg.x, v0.w, acc[g].w);
                acc[g].x = fmaf(xg.y, v1.x, acc[g].x);
                acc[g].y = fmaf(xg.y, v1.y, acc[g].y);
                acc[g].z = fmaf(xg.y, v1.z, acc[g].z);
                acc[g].w = fmaf(xg.y, v1.w, acc[g].w);
                acc[g].x = fmaf(xg.z, v2.x, acc[g].x);
                acc[g].y = fmaf(xg.z, v2.y, acc[g].y);
                acc[g].z = fmaf(xg.z, v2.z, acc[g].z);
                acc[g].w = fmaf(xg.z, v2.w, acc[g].w);
                acc[g].x = fmaf(xg.w, v3.x, acc[g].x);
                acc[g].y = fmaf(xg.w, v3.y, acc[g].y);
                acc[g].z = fmaf(xg.w, v3.z, acc[g].z);
                acc[g].w = fmaf(xg.w, v3.w, acc[g].w);
            }
        }

        #pragma unroll
        for (int g = 0; g < GT; ++g) {
            #pragma unroll
            for (int off = 8; off <= 32; off <<= 1) {
                acc[g].x += __shfl_xor(acc[g].x, off, 64);
                acc[g].y += __shfl_xor(acc[g].y, off, 64);
                acc[g].z += __shfl_xor(acc[g].z, off, 64);
                acc[g].w += __shfl_xor(acc[g].w, off, 64);
            }
        }
        const int wv = tid >> 6;
        if ((tid & 0x38) == 0) {
            #pragma unroll
            for (int g = 0; g < GT; ++g)
                *(float4*)&red[wv][pp4][g * 4] = acc[g];
        }
        __syncthreads();

        #pragma unroll
        for (int r = 0; r < 2; ++r) {
            const int idx = tid + r * BLOCK;
            const int g = idx >> 5, pp = idx & 31;
            const int q = pp >> 2, cmp = g * 4 + (pp & 3);
            const float s = red[0][q][cmp] + red[1][q][cmp]
                          + red[2][q][cmp] + red[3][q][cmp];
            partc[(size_t)gs[g] * PDIM + pp] = s;
        }
        __syncthreads();
    }
}

// ---------------------------------------------------------------------------
// K3 (R9): up-projection, d-split. Same de-staging: vu4 is read straight
// from global (perfectly coalesced 1 KB/wave per pp), reused from L1 across
// the 4 waves and across tiles. LDS drops 35.8 KB -> ~3 KB -> occupancy is
// VGPR-bound only (~6-8 blocks/CU).
template <int MODE>
__global__ __launch_bounds__(BLOCK, 4) void up_kernel(
    const float* __restrict__ vu,          // [NPAT, PDIM, DDIM]
    const int* __restrict__ offs,
    const int* __restrict__ etok,
    const float* __restrict__ ew,
    const float* __restrict__ part,        // [NCH][nent+1][PDIM]
    float* __restrict__ dst,               // contrib (MODE 0) or out (MODE 1)
    int nent)
{
    __shared__ float projT[PDIM][20];
    __shared__ int   gt[GT];
    __shared__ float gw[GT];
    __shared__ int   gs[GT];

    const int p   = blockIdx.x >> 2;
    const int c   = blockIdx.x & 3;
    const int tid = threadIdx.x;
    const int off0 = offs[p];
    const int n    = offs[p + 1] - off0;
    if (n == 0) return;

    const size_t PS = (size_t)(nent + 1) * PDIM;

    const float* vup = vu + (size_t)p * PDIM * DDIM + (size_t)c * DCH;

    const int gq   = tid >> 6;
    const int lane = tid & 63;

    for (int t0 = 0; t0 < n; t0 += GT) {
        const int gv = min(GT, n - t0);
        if (tid < GT) {
            if (tid < gv) {
                gt[tid] = etok[off0 + t0 + tid];
                gw[tid] = ew[off0 + t0 + tid];
                gs[tid] = off0 + t0 + tid;
            } else {
                gt[tid] = etok[off0]; gw[tid] = 0.f; gs[tid] = nent;
            }
        }
        __syncthreads();

        #pragma unroll
        for (int r = 0; r < 2; ++r) {
            const int idx = tid + r * BLOCK;
            const int g = idx >> 5, pp = idx & 31;
            const size_t row = (size_t)gs[g] * PDIM + pp;
            const float s = part[row] + part[PS + row]
                          + part[2 * PS + row] + part[3 * PS + row];
            const float pj = s / (1.f + expf(-s));
            projT[pp][g] = pj * gw[g];
        }
        __syncthreads();

        float4 o0 = make_float4(0.f, 0.f, 0.f, 0.f);
        float4 o1 = o0, o2 = o0, o3 = o0;
        #pragma unroll
        for (int pp = 0; pp < PDIM; ++pp) {
            const float4 pj4 = *(const float4*)&projT[pp][gq * 4];
            const float4 vu4 = *(const float4*)(vup + (size_t)pp * DDIM + lane * 4);
            o0.x = fmaf(pj4.x, vu4.x, o0.x); o0.y = fmaf(pj4.x, vu4.y, o0.y);
            o0.z = fmaf(pj4.x, vu4.z, o0.z); o0.w = fmaf(pj4.x, vu4.w, o0.w);
            o1.x = fmaf(pj4.y, vu4.x, o1.x); o1.y = fmaf(pj4.y, vu4.y, o1.y);
            o1.z = fmaf(pj4.y, vu4.z, o1.z); o1.w = fmaf(pj4.y, vu4.w, o1.w);
            o2.x = fmaf(pj4.z, vu4.x, o2.x); o2.y = fmaf(pj4.z, vu4.y, o2.y);
            o2.z = fmaf(pj4.z, vu4.z, o2.z); o2.w = fmaf(pj4.z, vu4.w, o2.w);
            o3.x = fmaf(pj4.w, vu4.x, o3.x); o3.y = fmaf(pj4.w, vu4.y, o3.y);
            o3.z = fmaf(pj4.w, vu4.z, o3.z); o3.w = fmaf(pj4.w, vu4.w, o3.w);
        }

        float4 ov[4] = {o0, o1, o2, o3};
        if (MODE == 0) {
            #pragma unroll
            for (int j = 0; j < 4; ++j)
                *(float4*)(dst + (size_t)gs[gq * 4 + j] * DDIM + c * DCH + lane * 4) = ov[j];
        } else {
            #pragma unroll
            for (int j = 0; j < 4; ++j) {
                const int g = gq * 4 + j;
                if (g < gv) {
                    float* op = dst + (size_t)gt[g] * DDIM + c * DCH + lane * 4;
                    atomicAdd(op + 0, ov[j].x);
                    atomicAdd(op + 1, ov[j].y);
                    atomicAdd(op + 2, ov[j].z);
                    atomicAdd(op + 3, ov[j].w);
                }
            }
        }
        __syncthreads();
    }
}

// ---------------------------------------------------------------------------
// K4: out[t] = x[t] + sum_k contrib[slotof[t][k]]  (verbatim-verified)
__global__ __launch_bounds__(BLOCK) void combine_kernel(
    const float* __restrict__ x, const float* __restrict__ contrib,
    const int* __restrict__ slotof, float* __restrict__ out)
{
    __shared__ int sl[TOPK];
    const int t = blockIdx.x, tid = threadIdx.x;
    if (tid < TOPK) sl[tid] = slotof[t * TOPK + tid];
    __syncthreads();
    float4 r = ((const float4*)(x + (size_t)t * DDIM))[tid];
    #pragma unroll
    for (int k = 0; k < TOPK; ++k) {
        const float4 cv = ((const float4*)(contrib + (size_t)sl[k] * DDIM))[tid];
        r.x += cv.x; r.y += cv.y; r.z += cv.z; r.w += cv.w;
    }
    ((float4*)(out + (size_t)t * DDIM))[tid] = r;
}

// ---------------------------------------------------------------------------
extern "C" void kernel_launch(void* const* d_in, const int* in_sizes, int n_in,
                              void* d_out, int out_size, void* d_ws, size_t ws_size,
                              hipStream_t stream) {
    const float* x        = (const float*)d_in[0];
    const float* hasher_w = (const float*)d_in[1];
    const float* keys     = (const float*)d_in[2];
    const float* vd       = (const float*)d_in[3];
    const float* vu       = (const float*)d_in[4];
    const float* scale    = (const float*)d_in[5];
    float* out = (float*)d_out;

    const int ntok = in_sizes[0] / DDIM;        // B*T
    const int nent = ntok * TOPK;

    // workspace layout
    char* w = (char*)d_ws;
    const size_t o_offs = 1024;                                   // 257 int
    const size_t o_tki  = 2560;                                   // nent int
    const size_t o_tkw  = o_tki  + (size_t)nent * 4;
    const size_t o_etok = o_tkw  + (size_t)nent * 4;
    const size_t o_ew   = o_etok + (size_t)nent * 4;
    const size_t o_slot = o_ew   + (size_t)nent * 4;
    const size_t o_part = (o_slot + (size_t)nent * 4 + 255) & ~(size_t)255;
    const size_t partsz = (size_t)NCH * (size_t)(nent + 1) * PDIM * 4;
    const size_t o_ctb  = (o_part + partsz + 255) & ~(size_t)255;
    const size_t needPart    = o_ctb;                              // atomic path
    const size_t needContrib = o_ctb + (size_t)(nent + 1) * DDIM * 4;

    int*   offs   = (int*)(w + o_offs);
    int*   tki    = (int*)(w + o_tki);
    float* tkw    = (float*)(w + o_tkw);
    int*   etok   = (int*)(w + o_etok);
    float* ew     = (float*)(w + o_ew);
    int*   slotof = (int*)(w + o_slot);
    float* part   = (float*)(w + o_part);
    float* contrib= (float*)(w + o_ctb);

    const int rblocks = (ntok + RTPB - 1) / RTPB;
    hipLaunchKernelGGL(route_kernel, dim3(rblocks), dim3(BLOCK), 0, stream,
                       x, hasher_w, keys, tki, tkw, ntok);
    hipLaunchKernelGGL(scanfill_kernel, dim3(1), dim3(NPAT), 0, stream,
                       tki, tkw, scale, offs, etok, ew, slotof, nent);
    hipLaunchKernelGGL(proj_kernel, dim3(NPAT * NCH), dim3(BLOCK), 0, stream,
                       x, vd, offs, etok, part, nent);

    if (ws_size >= needContrib) {
        hipLaunchKernelGGL((up_kernel<0>), dim3(NPAT * NCH), dim3(BLOCK), 0, stream,
                           vu, offs, etok, ew, part, contrib, nent);
        hipLaunchKernelGGL(combine_kernel, dim3(ntok), dim3(BLOCK), 0, stream,
                           x, contrib, slotof, out);
    } else if (ws_size >= needPart) {
        hipMemcpyAsync(out, x, (size_t)ntok * DDIM * 4, hipMemcpyDeviceToDevice,
                       stream);
        hipLaunchKernelGGL((up_kernel<1>), dim3(NPAT * NCH), dim3(BLOCK), 0, stream,
                           vu, offs, etok, ew, part, out, nent);
    }
}

// Round 3
// 216.109 us; speedup vs baseline: 1.8076x; 1.8076x over previous
//
#include <hip/hip_runtime.h>
#include <math.h>
#include <float.h>

#define DDIM 1024   // D
#define PDIM 32     // pattern_dim
#define NPAT 256    // n_patterns
#define TOPK 4
#define BLOCK 256
#define GT   16     // tokens per tile
#define DCH  256    // d-chunk per block
#define NCH  4      // d-chunks (DDIM/DCH)
#define RTPB 4      // tokens per route block (one per wave)

// ---------------------------------------------------------------------------
// K0 (R8): routing, one WAVE per token, 4 tokens/block, 512 blocks.
// (verbatim from the validated 235 us kernel)
__global__ __launch_bounds__(BLOCK) void route_kernel(
    const float* __restrict__ x,
    const float* __restrict__ hasher_w,   // [PDIM, DDIM]
    const float* __restrict__ keys,       // [NPAT, PDIM]
    int*   __restrict__ tki,              // [ntok, TOPK]
    float* __restrict__ tkw,              // [ntok, TOPK]
    int ntok)
{
    __shared__ float P_s[RTPB][64 * 33];  // 33.8 KB transpose scratch
    __shared__ float h_s[RTPB][32];

    const int tid  = threadIdx.x;
    const int wv   = tid >> 6;            // wave 0..3 = local token
    const int lane = tid & 63;
    const int tok  = min(blockIdx.x * RTPB + wv, ntok - 1);  // clamp (dup-write benign)

    // ---- x row into registers (coalesced float4)
    const float4* xrow = (const float4*)(x + (size_t)tok * DDIM);
    float4 xr[4];
    #pragma unroll
    for (int i = 0; i < 4; ++i) xr[i] = xrow[i * 64 + lane];

    // ---- per-lane partial h[pp] over this lane's 16 d's
    float part[PDIM];
    #pragma unroll
    for (int pp = 0; pp < PDIM; ++pp) {
        const float4* wrow = (const float4*)(hasher_w + (size_t)pp * DDIM);
        float a = 0.f;
        #pragma unroll
        for (int i = 0; i < 4; ++i) {
            const float4 w4 = wrow[i * 64 + lane];
            a = fmaf(xr[i].x, w4.x, a); a = fmaf(xr[i].y, w4.y, a);
            a = fmaf(xr[i].z, w4.z, a); a = fmaf(xr[i].w, w4.w, a);
        }
        part[pp] = a;
    }

    // ---- transpose-reduce: P[l][pp] -> h[pp]
    float* P = P_s[wv];
    #pragma unroll
    for (int pp = 0; pp < PDIM; ++pp) P[lane * 33 + pp] = part[pp];
    __syncthreads();

    {
        const int pp = lane & 31, half = lane >> 5;
        float hsum = 0.f;
        #pragma unroll 8
        for (int i = 0; i < 32; ++i)
            hsum += P[(half * 32 + i) * 33 + pp];
        hsum += __shfl_xor(hsum, 32, 64);
        if (half == 0) h_s[wv][pp] = hsum;
    }
    __syncthreads();

    // ---- sim + top4 + softmax (in-wave; verbatim logic from R7 phase 2)
    float4 h4[8];
    #pragma unroll
    for (int i = 0; i < 8; ++i) h4[i] = *(const float4*)&h_s[wv][i * 4];

    float sc0, sc1, sc2, sc3;
    {
        float sv[4];
        #pragma unroll
        for (int c = 0; c < 4; ++c) {
            const float4* kr = (const float4*)(keys + (size_t)(c * 64 + lane) * PDIM);
            float a = 0.f;
            #pragma unroll
            for (int i = 0; i < 8; ++i) {
                const float4 k4 = kr[i];
                a = fmaf(k4.x, h4[i].x, a); a = fmaf(k4.y, h4[i].y, a);
                a = fmaf(k4.z, h4[i].z, a); a = fmaf(k4.w, h4[i].w, a);
            }
            sv[c] = a;
        }
        sc0 = sv[0]; sc1 = sv[1]; sc2 = sv[2]; sc3 = sv[3];
    }

    float wval[TOPK]; int widx[TOPK];
    #pragma unroll
    for (int r = 0; r < TOPK; ++r) {
        float bv = sc0; int bc = 0;
        if (sc1 > bv) { bv = sc1; bc = 1; }
        if (sc2 > bv) { bv = sc2; bc = 2; }
        if (sc3 > bv) { bv = sc3; bc = 3; }
        int bidx = bc * 64 + lane;
        #pragma unroll
        for (int off = 1; off < 64; off <<= 1) {
            const float ov = __shfl_xor(bv, off, 64);
            const int   oi = __shfl_xor(bidx, off, 64);
            if (ov > bv || (ov == bv && oi < bidx)) { bv = ov; bidx = oi; }
        }
        wval[r] = bv; widx[r] = bidx;
        if ((bidx & 63) == lane) {
            const int c = bidx >> 6;
            if (c == 0) sc0 = -FLT_MAX;
            else if (c == 1) sc1 = -FLT_MAX;
            else if (c == 2) sc2 = -FLT_MAX;
            else sc3 = -FLT_MAX;
        }
    }

    if (lane == 0) {
        float m = wval[0];
        #pragma unroll
        for (int k = 1; k < TOPK; ++k) m = fmaxf(m, wval[k]);
        float s = 0.f, e[TOPK];
        #pragma unroll
        for (int k = 0; k < TOPK; ++k) { e[k] = expf(wval[k] - m); s += e[k]; }
        #pragma unroll
        for (int k = 0; k < TOPK; ++k) {
            tki[tok * TOPK + k] = widx[k];
            tkw[tok * TOPK + k] = e[k] / s;
        }
    }
}

// ---------------------------------------------------------------------------
// K1 (R10): count + scan + CSR fill, PLUS tile decomposition:
// tile2p[t] = pattern of tile t, tilei[t] = tile index within pattern.
// Tiles = ceil(n_p/GT) per pattern, scanned to a flat list. Unused slots
// (t >= total tiles) get tile2p = -1 so proj/up blocks early-return.
__global__ __launch_bounds__(NPAT) void scanfill_kernel(
    const int* __restrict__ tki, const float* __restrict__ tkw,
    const float* __restrict__ scale_p,
    int* __restrict__ offs,
    int* __restrict__ etok, float* __restrict__ ew, int* __restrict__ slotof,
    int* __restrict__ tile2p, int* __restrict__ tilei,
    int nent, int maxt)
{
    __shared__ int s[NPAT];
    __shared__ int cur[NPAT];
    const int tid = threadIdx.x;

    cur[tid] = 0;
    __syncthreads();
    for (int e = tid; e < nent; e += NPAT) atomicAdd(&cur[tki[e]], 1);
    __syncthreads();

    const int v = cur[tid];
    s[tid] = v;
    __syncthreads();
    for (int off = 1; off < NPAT; off <<= 1) {
        int t = 0;
        if (tid >= off) t = s[tid - off];
        __syncthreads();
        s[tid] += t;
        __syncthreads();
    }
    const int incl = s[tid];
    offs[tid + 1] = incl;
    if (tid == 0) offs[0] = 0;
    cur[tid] = incl - v;
    __syncthreads();

    // ---- tile decomposition: second scan over ceil(n/GT)
    const int tc = (v + GT - 1) / GT;
    s[tid] = tc;
    __syncthreads();
    for (int off = 1; off < NPAT; off <<= 1) {
        int t = 0;
        if (tid >= off) t = s[tid - off];
        __syncthreads();
        s[tid] += t;
        __syncthreads();
    }
    const int toff = s[tid] - tc;
    for (int i = tid; i < maxt; i += NPAT) tile2p[i] = -1;
    __syncthreads();
    for (int i = 0; i < tc; ++i) { tile2p[toff + i] = tid; tilei[toff + i] = i; }

    // ---- CSR fill (independent of tile fill; no sync needed between)
    const float sc = scale_p[0];
    for (int e = tid; e < nent; e += NPAT) {
        const int p = tki[e];
        const int slot = atomicAdd(&cur[p], 1);
        etok[slot] = e >> 2;
        ew[slot]   = tkw[e] * sc;
        slotof[e]  = slot;
    }
}

// ---------------------------------------------------------------------------
// K2 (R10): down-projection, ONE TILE per block (load-balanced), LDS-staged
// vd panel (R8-verified inner body). blockIdx = tile*NCH + chunk.
__global__ __launch_bounds__(BLOCK, 2) void proj_kernel(
    const float* __restrict__ x,
    const float* __restrict__ vd,          // [NPAT, DDIM, PDIM]
    const int* __restrict__ offs,
    const int* __restrict__ etok,
    const int* __restrict__ tile2p,
    const int* __restrict__ tilei,
    float* __restrict__ part,              // [NCH][nent+1][PDIM]
    int nent)
{
    __shared__ float vd_s[DCH * PDIM];     // 32 KB
    __shared__ float x_s[GT * DCH];        // 16 KB
    __shared__ float red[4][8][68];        // 8.7 KB
    __shared__ int   gt[GT];
    __shared__ int   gs[GT];

    const int tb  = blockIdx.x >> 2;
    const int c   = blockIdx.x & 3;
    const int p   = tile2p[tb];
    if (p < 0) return;
    const int tid = threadIdx.x;
    const int off0 = offs[p] + tilei[tb] * GT;
    const int gv   = min(GT, offs[p + 1] - off0);

    const float* vdp = vd + (size_t)p * DDIM * PDIM + (size_t)c * DCH * PDIM;
    #pragma unroll
    for (int k = 0; k < 8; ++k)
        ((float4*)vd_s)[k * 256 + tid] = ((const float4*)vdp)[k * 256 + tid];

    if (tid < GT) {
        if (tid < gv) { gt[tid] = etok[off0 + tid]; gs[tid] = off0 + tid; }
        else          { gt[tid] = etok[off0];       gs[tid] = nent; }
    }
    __syncthreads();

    #pragma unroll
    for (int k = 0; k < 4; ++k) {
        const int q  = k * 256 + tid;
        const int g  = q >> 6, fi = q & 63;
        ((float4*)x_s)[g * 64 + fi] =
            *(const float4*)(x + (size_t)gt[g] * DDIM + c * DCH + fi * 4);
    }
    __syncthreads();

    const int pp4 = tid & 7;
    const int seg = tid >> 3;
    float* partc = part + (size_t)c * (size_t)(nent + 1) * PDIM;

    float4 acc[GT];
    #pragma unroll
    for (int g = 0; g < GT; ++g) acc[g] = make_float4(0.f, 0.f, 0.f, 0.f);

    #pragma unroll
    for (int i4 = 0; i4 < 2; ++i4) {
        const int d0 = seg * 8 + i4 * 4;
        const float4 v0 = *(const float4*)&vd_s[(d0 + 0) * PDIM + pp4 * 4];
        const float4 v1 = *(const float4*)&vd_s[(d0 + 1) * PDIM + pp4 * 4];
        const float4 v2 = *(const float4*)&vd_s[(d0 + 2) * PDIM + pp4 * 4];
        const float4 v3 = *(const float4*)&vd_s[(d0 + 3) * PDIM + pp4 * 4];
        #pragma unroll
        for (int g = 0; g < GT; ++g) {
            const float4 xg = *(const float4*)&x_s[g * DCH + d0];
            acc[g].x = fmaf(xg.x, v0.x, acc[g].x);
            acc[g].y = fmaf(xg.x, v0.y, acc[g].y);
            acc[g].z = fmaf(xg.x, v0.z, acc[g].z);
            acc[g].w = fmaf(xg.x, v0.w, acc[g].w);
            acc[g].x = fmaf(xg.y, v1.x, acc[g].x);
            acc[g].y = fmaf(xg.y, v1.y, acc[g].y);
            acc[g].z = fmaf(xg.y, v1.z, acc[g].z);
            acc[g].w = fmaf(xg.y, v1.w, acc[g].w);
            acc[g].x = fmaf(xg.z, v2.x, acc[g].x);
            acc[g].y = fmaf(xg.z, v2.y, acc[g].y);
            acc[g].z = fmaf(xg.z, v2.z, acc[g].z);
            acc[g].w = fmaf(xg.z, v2.w, acc[g].w);
            acc[g].x = fmaf(xg.w, v3.x, acc[g].x);
            acc[g].y = fmaf(xg.w, v3.y, acc[g].y);
            acc[g].z = fmaf(xg.w, v3.z, acc[g].z);
            acc[g].w = fmaf(xg.w, v3.w, acc[g].w);
        }
    }

    #pragma unroll
    for (int g = 0; g < GT; ++g) {
        #pragma unroll
        for (int off = 8; off <= 32; off <<= 1) {
            acc[g].x += __shfl_xor(acc[g].x, off, 64);
            acc[g].y += __shfl_xor(acc[g].y, off, 64);
            acc[g].z += __shfl_xor(acc[g].z, off, 64);
            acc[g].w += __shfl_xor(acc[g].w, off, 64);
        }
    }
    const int wv = tid >> 6;
    if ((tid & 0x38) == 0) {
        #pragma unroll
        for (int g = 0; g < GT; ++g)
            *(float4*)&red[wv][pp4][g * 4] = acc[g];
    }
    __syncthreads();

    #pragma unroll
    for (int r = 0; r < 2; ++r) {
        const int idx = tid + r * BLOCK;
        const int g = idx >> 5, pp = idx & 31;
        const int q = pp >> 2, cmp = g * 4 + (pp & 3);
        const float s = red[0][q][cmp] + red[1][q][cmp]
                      + red[2][q][cmp] + red[3][q][cmp];
        partc[(size_t)gs[g] * PDIM + pp] = s;
    }
}

// ---------------------------------------------------------------------------
// K3 (R10): up-projection, ONE TILE per block, LDS-staged vu panel
// (R8-verified inner body).
template <int MODE>
__global__ __launch_bounds__(BLOCK, 4) void up_kernel(
    const float* __restrict__ vu,          // [NPAT, PDIM, DDIM]
    const int* __restrict__ offs,
    const int* __restrict__ etok,
    const float* __restrict__ ew,
    const int* __restrict__ tile2p,
    const int* __restrict__ tilei,
    const float* __restrict__ part,        // [NCH][nent+1][PDIM]
    float* __restrict__ dst,               // contrib (MODE 0) or out (MODE 1)
    int nent)
{
    __shared__ float vu_s[PDIM * DCH];     // 32 KB
    __shared__ float projT[PDIM][20];
    __shared__ int   gt[GT];
    __shared__ float gw[GT];
    __shared__ int   gs[GT];

    const int tb  = blockIdx.x >> 2;
    const int c   = blockIdx.x & 3;
    const int p   = tile2p[tb];
    if (p < 0) return;
    const int tid = threadIdx.x;
    const int off0 = offs[p] + tilei[tb] * GT;
    const int gv   = min(GT, offs[p + 1] - off0);

    const size_t PS = (size_t)(nent + 1) * PDIM;

    const float* vup = vu + (size_t)p * PDIM * DDIM + (size_t)c * DCH;
    #pragma unroll
    for (int k = 0; k < 8; ++k) {
        const int q  = k * 256 + tid;
        const int pp = q >> 6, fi = q & 63;
        *(float4*)&vu_s[pp * DCH + fi * 4] =
            *(const float4*)(vup + (size_t)pp * DDIM + fi * 4);
    }
    if (tid < GT) {
        if (tid < gv) {
            gt[tid] = etok[off0 + tid];
            gw[tid] = ew[off0 + tid];
            gs[tid] = off0 + tid;
        } else {
            gt[tid] = etok[off0]; gw[tid] = 0.f; gs[tid] = nent;
        }
    }
    __syncthreads();

    const int gq   = tid >> 6;
    const int lane = tid & 63;

    #pragma unroll
    for (int r = 0; r < 2; ++r) {
        const int idx = tid + r * BLOCK;
        const int g = idx >> 5, pp = idx & 31;
        const size_t row = (size_t)gs[g] * PDIM + pp;
        const float s = part[row] + part[PS + row]
                      + part[2 * PS + row] + part[3 * PS + row];
        const float pj = s / (1.f + expf(-s));
        projT[pp][g] = pj * gw[g];
    }
    __syncthreads();

    float4 o0 = make_float4(0.f, 0.f, 0.f, 0.f);
    float4 o1 = o0, o2 = o0, o3 = o0;
    #pragma unroll
    for (int pp = 0; pp < PDIM; ++pp) {
        const float4 pj4 = *(const float4*)&projT[pp][gq * 4];
        const float4 vu4 = *(const float4*)&vu_s[pp * DCH + lane * 4];
        o0.x = fmaf(pj4.x, vu4.x, o0.x); o0.y = fmaf(pj4.x, vu4.y, o0.y);
        o0.z = fmaf(pj4.x, vu4.z, o0.z); o0.w = fmaf(pj4.x, vu4.w, o0.w);
        o1.x = fmaf(pj4.y, vu4.x, o1.x); o1.y = fmaf(pj4.y, vu4.y, o1.y);
        o1.z = fmaf(pj4.y, vu4.z, o1.z); o1.w = fmaf(pj4.y, vu4.w, o1.w);
        o2.x = fmaf(pj4.z, vu4.x, o2.x); o2.y = fmaf(pj4.z, vu4.y, o2.y);
        o2.z = fmaf(pj4.z, vu4.z, o2.z); o2.w = fmaf(pj4.z, vu4.w, o2.w);
        o3.x = fmaf(pj4.w, vu4.x, o3.x); o3.y = fmaf(pj4.w, vu4.y, o3.y);
        o3.z = fmaf(pj4.w, vu4.z, o3.z); o3.w = fmaf(pj4.w, vu4.w, o3.w);
    }

    float4 ov[4] = {o0, o1, o2, o3};
    if (MODE == 0) {
        #pragma unroll
        for (int j = 0; j < 4; ++j)
            *(float4*)(dst + (size_t)gs[gq * 4 + j] * DDIM + c * DCH + lane * 4) = ov[j];
    } else {
        #pragma unroll
        for (int j = 0; j < 4; ++j) {
            const int g = gq * 4 + j;
            if (g < gv) {
                float* op = dst + (size_t)gt[g] * DDIM + c * DCH + lane * 4;
                atomicAdd(op + 0, ov[j].x);
                atomicAdd(op + 1, ov[j].y);
                atomicAdd(op + 2, ov[j].z);
                atomicAdd(op + 3, ov[j].w);
            }
        }
    }
}

// ---------------------------------------------------------------------------
// K4: out[t] = x[t] + sum_k contrib[slotof[t][k]]  (verbatim-verified)
__global__ __launch_bounds__(BLOCK) void combine_kernel(
    const float* __restrict__ x, const float* __restrict__ contrib,
    const int* __restrict__ slotof, float* __restrict__ out)
{
    __shared__ int sl[TOPK];
    const int t = blockIdx.x, tid = threadIdx.x;
    if (tid < TOPK) sl[tid] = slotof[t * TOPK + tid];
    __syncthreads();
    float4 r = ((const float4*)(x + (size_t)t * DDIM))[tid];
    #pragma unroll
    for (int k = 0; k < TOPK; ++k) {
        const float4 cv = ((const float4*)(contrib + (size_t)sl[k] * DDIM))[tid];
        r.x += cv.x; r.y += cv.y; r.z += cv.z; r.w += cv.w;
    }
    ((float4*)(out + (size_t)t * DDIM))[tid] = r;
}

// ---------------------------------------------------------------------------
extern "C" void kernel_launch(void* const* d_in, const int* in_sizes, int n_in,
                              void* d_out, int out_size, void* d_ws, size_t ws_size,
                              hipStream_t stream) {
    const float* x        = (const float*)d_in[0];
    const float* hasher_w = (const float*)d_in[1];
    const float* keys     = (const float*)d_in[2];
    const float* vd       = (const float*)d_in[3];
    const float* vu       = (const float*)d_in[4];
    const float* scale    = (const float*)d_in[5];
    float* out = (float*)d_out;

    const int ntok = in_sizes[0] / DDIM;        // B*T
    if (ntok <= 0) return;
    const int nent = ntok * TOPK;
    const int maxt = (nent + GT - 1) / GT + NPAT;   // worst-case tile count

    // workspace layout
    char* w = (char*)d_ws;
    const size_t o_offs = 1024;                                   // 257 int
    const size_t o_tki  = 2560;                                   // nent int
    const size_t o_tkw  = o_tki  + (size_t)nent * 4;
    const size_t o_etok = o_tkw  + (size_t)nent * 4;
    const size_t o_ew   = o_etok + (size_t)nent * 4;
    const size_t o_slot = o_ew   + (size_t)nent * 4;
    const size_t o_t2p  = o_slot + (size_t)nent * 4;
    const size_t o_tli  = o_t2p  + (size_t)maxt * 4;
    const size_t o_part = (o_tli + (size_t)maxt * 4 + 255) & ~(size_t)255;
    const size_t partsz = (size_t)NCH * (size_t)(nent + 1) * PDIM * 4;
    const size_t o_ctb  = (o_part + partsz + 255) & ~(size_t)255;
    const size_t needPart    = o_ctb;                              // atomic path
    const size_t needContrib = o_ctb + (size_t)(nent + 1) * DDIM * 4;

    int*   offs   = (int*)(w + o_offs);
    int*   tki    = (int*)(w + o_tki);
    float* tkw    = (float*)(w + o_tkw);
    int*   etok   = (int*)(w + o_etok);
    float* ew     = (float*)(w + o_ew);
    int*   slotof = (int*)(w + o_slot);
    int*   tile2p = (int*)(w + o_t2p);
    int*   tilei  = (int*)(w + o_tli);
    float* part   = (float*)(w + o_part);
    float* contrib= (float*)(w + o_ctb);

    const int rblocks = (ntok + RTPB - 1) / RTPB;
    hipLaunchKernelGGL(route_kernel, dim3(rblocks), dim3(BLOCK), 0, stream,
                       x, hasher_w, keys, tki, tkw, ntok);
    hipLaunchKernelGGL(scanfill_kernel, dim3(1), dim3(NPAT), 0, stream,
                       tki, tkw, scale, offs, etok, ew, slotof,
                       tile2p, tilei, nent, maxt);
    hipLaunchKernelGGL(proj_kernel, dim3(maxt * NCH), dim3(BLOCK), 0, stream,
                       x, vd, offs, etok, tile2p, tilei, part, nent);

    if (ws_size >= needContrib) {
        hipLaunchKernelGGL((up_kernel<0>), dim3(maxt * NCH), dim3(BLOCK), 0, stream,
                           vu, offs, etok, ew, tile2p, tilei, part, contrib, nent);
        hipLaunchKernelGGL(combine_kernel, dim3(ntok), dim3(BLOCK), 0, stream,
                           x, contrib, slotof, out);
    } else if (ws_size >= needPart) {
        hipMemcpyAsync(out, x, (size_t)ntok * DDIM * 4, hipMemcpyDeviceToDevice,
                       stream);
        hipLaunchKernelGGL((up_kernel<1>), dim3(maxt * NCH), dim3(BLOCK), 0, stream,
                           vu, offs, etok, ew, tile2p, tilei, part, out, nent);
    }
}

// Round 4
// 208.858 us; speedup vs baseline: 1.8704x; 1.0347x over previous
//
#include <hip/hip_runtime.h>
#include <math.h>
#include <float.h>

#define DDIM 1024   // D
#define PDIM 32     // pattern_dim
#define NPAT 256    // n_patterns
#define TOPK 4
#define BLOCK 256
#define GT   16     // tokens per tile
#define DCHP 128    // d-chunk per block (proj & up)
#define NCHP 8      // d-chunks (DDIM/DCHP)
#define RTPB 4      // tokens per route block (one per wave)

// ---------------------------------------------------------------------------
// K0 (R8): routing, one WAVE per token, 4 tokens/block, 512 blocks.
// (verbatim from the validated 235 us kernel)
__global__ __launch_bounds__(BLOCK) void route_kernel(
    const float* __restrict__ x,
    const float* __restrict__ hasher_w,   // [PDIM, DDIM]
    const float* __restrict__ keys,       // [NPAT, PDIM]
    int*   __restrict__ tki,              // [ntok, TOPK]
    float* __restrict__ tkw,              // [ntok, TOPK]
    int ntok)
{
    __shared__ float P_s[RTPB][64 * 33];  // 33.8 KB transpose scratch
    __shared__ float h_s[RTPB][32];

    const int tid  = threadIdx.x;
    const int wv   = tid >> 6;            // wave 0..3 = local token
    const int lane = tid & 63;
    const int tok  = min(blockIdx.x * RTPB + wv, ntok - 1);  // clamp (dup-write benign)

    // ---- x row into registers (coalesced float4)
    const float4* xrow = (const float4*)(x + (size_t)tok * DDIM);
    float4 xr[4];
    #pragma unroll
    for (int i = 0; i < 4; ++i) xr[i] = xrow[i * 64 + lane];

    // ---- per-lane partial h[pp] over this lane's 16 d's
    float part[PDIM];
    #pragma unroll
    for (int pp = 0; pp < PDIM; ++pp) {
        const float4* wrow = (const float4*)(hasher_w + (size_t)pp * DDIM);
        float a = 0.f;
        #pragma unroll
        for (int i = 0; i < 4; ++i) {
            const float4 w4 = wrow[i * 64 + lane];
            a = fmaf(xr[i].x, w4.x, a); a = fmaf(xr[i].y, w4.y, a);
            a = fmaf(xr[i].z, w4.z, a); a = fmaf(xr[i].w, w4.w, a);
        }
        part[pp] = a;
    }

    // ---- transpose-reduce: P[l][pp] -> h[pp]
    float* P = P_s[wv];
    #pragma unroll
    for (int pp = 0; pp < PDIM; ++pp) P[lane * 33 + pp] = part[pp];
    __syncthreads();

    {
        const int pp = lane & 31, half = lane >> 5;
        float hsum = 0.f;
        #pragma unroll 8
        for (int i = 0; i < 32; ++i)
            hsum += P[(half * 32 + i) * 33 + pp];
        hsum += __shfl_xor(hsum, 32, 64);
        if (half == 0) h_s[wv][pp] = hsum;
    }
    __syncthreads();

    // ---- sim + top4 + softmax (in-wave; verbatim logic from R7 phase 2)
    float4 h4[8];
    #pragma unroll
    for (int i = 0; i < 8; ++i) h4[i] = *(const float4*)&h_s[wv][i * 4];

    float sc0, sc1, sc2, sc3;
    {
        float sv[4];
        #pragma unroll
        for (int c = 0; c < 4; ++c) {
            const float4* kr = (const float4*)(keys + (size_t)(c * 64 + lane) * PDIM);
            float a = 0.f;
            #pragma unroll
            for (int i = 0; i < 8; ++i) {
                const float4 k4 = kr[i];
                a = fmaf(k4.x, h4[i].x, a); a = fmaf(k4.y, h4[i].y, a);
                a = fmaf(k4.z, h4[i].z, a); a = fmaf(k4.w, h4[i].w, a);
            }
            sv[c] = a;
        }
        sc0 = sv[0]; sc1 = sv[1]; sc2 = sv[2]; sc3 = sv[3];
    }

    float wval[TOPK]; int widx[TOPK];
    #pragma unroll
    for (int r = 0; r < TOPK; ++r) {
        float bv = sc0; int bc = 0;
        if (sc1 > bv) { bv = sc1; bc = 1; }
        if (sc2 > bv) { bv = sc2; bc = 2; }
        if (sc3 > bv) { bv = sc3; bc = 3; }
        int bidx = bc * 64 + lane;
        #pragma unroll
        for (int off = 1; off < 64; off <<= 1) {
            const float ov = __shfl_xor(bv, off, 64);
            const int   oi = __shfl_xor(bidx, off, 64);
            if (ov > bv || (ov == bv && oi < bidx)) { bv = ov; bidx = oi; }
        }
        wval[r] = bv; widx[r] = bidx;
        if ((bidx & 63) == lane) {
            const int c = bidx >> 6;
            if (c == 0) sc0 = -FLT_MAX;
            else if (c == 1) sc1 = -FLT_MAX;
            else if (c == 2) sc2 = -FLT_MAX;
            else sc3 = -FLT_MAX;
        }
    }

    if (lane == 0) {
        float m = wval[0];
        #pragma unroll
        for (int k = 1; k < TOPK; ++k) m = fmaxf(m, wval[k]);
        float s = 0.f, e[TOPK];
        #pragma unroll
        for (int k = 0; k < TOPK; ++k) { e[k] = expf(wval[k] - m); s += e[k]; }
        #pragma unroll
        for (int k = 0; k < TOPK; ++k) {
            tki[tok * TOPK + k] = widx[k];
            tkw[tok * TOPK + k] = e[k] / s;
        }
    }
}

// ---------------------------------------------------------------------------
// K1 (R10): count + scan + CSR fill + tile decomposition (R3-verified).
__global__ __launch_bounds__(NPAT) void scanfill_kernel(
    const int* __restrict__ tki, const float* __restrict__ tkw,
    const float* __restrict__ scale_p,
    int* __restrict__ offs,
    int* __restrict__ etok, float* __restrict__ ew, int* __restrict__ slotof,
    int* __restrict__ tile2p, int* __restrict__ tilei,
    int nent, int maxt)
{
    __shared__ int s[NPAT];
    __shared__ int cur[NPAT];
    const int tid = threadIdx.x;

    cur[tid] = 0;
    __syncthreads();
    for (int e = tid; e < nent; e += NPAT) atomicAdd(&cur[tki[e]], 1);
    __syncthreads();

    const int v = cur[tid];
    s[tid] = v;
    __syncthreads();
    for (int off = 1; off < NPAT; off <<= 1) {
        int t = 0;
        if (tid >= off) t = s[tid - off];
        __syncthreads();
        s[tid] += t;
        __syncthreads();
    }
    const int incl = s[tid];
    offs[tid + 1] = incl;
    if (tid == 0) offs[0] = 0;
    cur[tid] = incl - v;
    __syncthreads();

    // ---- tile decomposition: second scan over ceil(n/GT)
    const int tc = (v + GT - 1) / GT;
    s[tid] = tc;
    __syncthreads();
    for (int off = 1; off < NPAT; off <<= 1) {
        int t = 0;
        if (tid >= off) t = s[tid - off];
        __syncthreads();
        s[tid] += t;
        __syncthreads();
    }
    const int toff = s[tid] - tc;
    for (int i = tid; i < maxt; i += NPAT) tile2p[i] = -1;
    __syncthreads();
    for (int i = 0; i < tc; ++i) { tile2p[toff + i] = tid; tilei[toff + i] = i; }

    // ---- CSR fill
    const float sc = scale_p[0];
    for (int e = tid; e < nent; e += NPAT) {
        const int p = tki[e];
        const int slot = atomicAdd(&cur[p], 1);
        etok[slot] = e >> 2;
        ew[slot]   = tkw[e] * sc;
        slotof[e]  = slot;
    }
}

// ---------------------------------------------------------------------------
// K2 (R11): down-projection. One tile x one 128-d chunk per block.
// LDS 24.4 KB -> ~6 blocks/CU. Each WAVE owns 4 tokens and the full 128-d
// chunk: per-lane partial over its 16 d's, shuffle-reduce over 8 segs,
// direct float4 store to part (no cross-wave LDS reduction).
__global__ __launch_bounds__(BLOCK, 6) void proj_kernel(
    const float* __restrict__ x,
    const float* __restrict__ vd,          // [NPAT, DDIM, PDIM]
    const int* __restrict__ offs,
    const int* __restrict__ etok,
    const int* __restrict__ tile2p,
    const int* __restrict__ tilei,
    float* __restrict__ part,              // [NCHP][nent+1][PDIM]
    int nent)
{
    __shared__ float vd_s[DCHP * PDIM];    // 16 KB
    __shared__ float x_s[GT * DCHP];       // 8 KB
    __shared__ int   gt[GT];
    __shared__ int   gs[GT];

    const int tb  = blockIdx.x >> 3;
    const int c   = blockIdx.x & 7;
    const int p   = tile2p[tb];
    if (p < 0) return;
    const int tid = threadIdx.x;
    const int off0 = offs[p] + tilei[tb] * GT;
    const int gv   = min(GT, offs[p + 1] - off0);

    // stage vd panel chunk: 128 x 32 floats = 16 KB
    const float* vdp = vd + (size_t)p * DDIM * PDIM + (size_t)c * DCHP * PDIM;
    #pragma unroll
    for (int k = 0; k < 4; ++k)
        ((float4*)vd_s)[k * 256 + tid] = ((const float4*)vdp)[k * 256 + tid];

    if (tid < GT) {
        if (tid < gv) { gt[tid] = etok[off0 + tid]; gs[tid] = off0 + tid; }
        else          { gt[tid] = etok[off0];       gs[tid] = nent; }
    }
    __syncthreads();

    // stage x tile chunk: 16 tokens x 128 floats = 8 KB
    #pragma unroll
    for (int k = 0; k < 2; ++k) {
        const int q  = k * 256 + tid;
        const int g  = q >> 5, fi = q & 31;
        ((float4*)x_s)[g * 32 + fi] =
            *(const float4*)(x + (size_t)gt[g] * DDIM + c * DCHP + fi * 4);
    }
    __syncthreads();

    const int lane = tid & 63;
    const int wv   = tid >> 6;            // wave -> tokens wv*4 .. wv*4+3
    const int pp4  = lane & 7;            // pp-quad
    const int seg  = lane >> 3;           // 8 segs x 16 d = 128 d

    float4 acc[4];
    #pragma unroll
    for (int j = 0; j < 4; ++j) acc[j] = make_float4(0.f, 0.f, 0.f, 0.f);

    #pragma unroll
    for (int i4 = 0; i4 < 4; ++i4) {
        const int d0 = seg * 16 + i4 * 4;
        const float4 v0 = *(const float4*)&vd_s[(d0 + 0) * PDIM + pp4 * 4];
        const float4 v1 = *(const float4*)&vd_s[(d0 + 1) * PDIM + pp4 * 4];
        const float4 v2 = *(const float4*)&vd_s[(d0 + 2) * PDIM + pp4 * 4];
        const float4 v3 = *(const float4*)&vd_s[(d0 + 3) * PDIM + pp4 * 4];
        #pragma unroll
        for (int j = 0; j < 4; ++j) {
            const float4 xg = *(const float4*)&x_s[(wv * 4 + j) * DCHP + d0];
            acc[j].x = fmaf(xg.x, v0.x, acc[j].x);
            acc[j].y = fmaf(xg.x, v0.y, acc[j].y);
            acc[j].z = fmaf(xg.x, v0.z, acc[j].z);
            acc[j].w = fmaf(xg.x, v0.w, acc[j].w);
            acc[j].x = fmaf(xg.y, v1.x, acc[j].x);
            acc[j].y = fmaf(xg.y, v1.y, acc[j].y);
            acc[j].z = fmaf(xg.y, v1.z, acc[j].z);
            acc[j].w = fmaf(xg.y, v1.w, acc[j].w);
            acc[j].x = fmaf(xg.z, v2.x, acc[j].x);
            acc[j].y = fmaf(xg.z, v2.y, acc[j].y);
            acc[j].z = fmaf(xg.z, v2.z, acc[j].z);
            acc[j].w = fmaf(xg.z, v2.w, acc[j].w);
            acc[j].x = fmaf(xg.w, v3.x, acc[j].x);
            acc[j].y = fmaf(xg.w, v3.y, acc[j].y);
            acc[j].z = fmaf(xg.w, v3.z, acc[j].z);
            acc[j].w = fmaf(xg.w, v3.w, acc[j].w);
        }
    }

    // reduce over the 8 segs of the wave
    #pragma unroll
    for (int j = 0; j < 4; ++j) {
        #pragma unroll
        for (int off = 8; off <= 32; off <<= 1) {
            acc[j].x += __shfl_xor(acc[j].x, off, 64);
            acc[j].y += __shfl_xor(acc[j].y, off, 64);
            acc[j].z += __shfl_xor(acc[j].z, off, 64);
            acc[j].w += __shfl_xor(acc[j].w, off, 64);
        }
    }

    float* partc = part + (size_t)c * (size_t)(nent + 1) * PDIM;
    if ((lane & 0x38) == 0) {  // seg == 0: 8 lanes hold pp4 quads
        #pragma unroll
        for (int j = 0; j < 4; ++j)
            *(float4*)&partc[(size_t)gs[wv * 4 + j] * PDIM + pp4 * 4] = acc[j];
    }
}

// ---------------------------------------------------------------------------
// K3 (R11): up-projection. One tile x one 128-d chunk per block.
// LDS ~19 KB -> up to 8 blocks/CU. Half-wave (32 lanes) covers the 128-d
// chunk; each thread produces 2 tokens.
template <int MODE>
__global__ __launch_bounds__(BLOCK, 6) void up_kernel(
    const float* __restrict__ vu,          // [NPAT, PDIM, DDIM]
    const int* __restrict__ offs,
    const int* __restrict__ etok,
    const float* __restrict__ ew,
    const int* __restrict__ tile2p,
    const int* __restrict__ tilei,
    const float* __restrict__ part,        // [NCHP][nent+1][PDIM]
    float* __restrict__ dst,               // contrib (MODE 0) or out (MODE 1)
    int nent)
{
    __shared__ float vu_s[PDIM * DCHP];    // 16 KB
    __shared__ float projT[PDIM][20];
    __shared__ int   gt[GT];
    __shared__ float gw[GT];
    __shared__ int   gs[GT];

    const int tb  = blockIdx.x >> 3;
    const int c   = blockIdx.x & 7;
    const int p   = tile2p[tb];
    if (p < 0) return;
    const int tid = threadIdx.x;
    const int off0 = offs[p] + tilei[tb] * GT;
    const int gv   = min(GT, offs[p + 1] - off0);

    const size_t PS = (size_t)(nent + 1) * PDIM;

    // stage vu panel chunk: 32 x 128 floats = 16 KB
    const float* vup = vu + (size_t)p * PDIM * DDIM + (size_t)c * DCHP;
    #pragma unroll
    for (int k = 0; k < 4; ++k) {
        const int q  = k * 256 + tid;
        const int pp = q >> 5, fi = q & 31;
        *(float4*)&vu_s[pp * DCHP + fi * 4] =
            *(const float4*)(vup + (size_t)pp * DDIM + fi * 4);
    }
    if (tid < GT) {
        if (tid < gv) {
            gt[tid] = etok[off0 + tid];
            gw[tid] = ew[off0 + tid];
            gs[tid] = off0 + tid;
        } else {
            gt[tid] = etok[off0]; gw[tid] = 0.f; gs[tid] = nent;
        }
    }
    __syncthreads();

    // silu(sum of 8 partials) * weight -> projT
    #pragma unroll
    for (int r = 0; r < 2; ++r) {
        const int idx = tid + r * BLOCK;
        const int g = idx >> 5, pp = idx & 31;
        const size_t row = (size_t)gs[g] * PDIM + pp;
        float s = 0.f;
        #pragma unroll
        for (int i = 0; i < NCHP; ++i) s += part[i * PS + row];
        const float pj = s / (1.f + expf(-s));
        projT[pp][g] = pj * gw[g];
    }
    __syncthreads();

    const int tg  = tid >> 5;              // 0..7: token pair group
    const int l32 = tid & 31;              // covers 128 d as float4
    const int g0 = tg * 2, g1 = tg * 2 + 1;

    float4 o0 = make_float4(0.f, 0.f, 0.f, 0.f);
    float4 o1 = o0;
    #pragma unroll
    for (int pp = 0; pp < PDIM; ++pp) {
        const float4 vu4 = *(const float4*)&vu_s[pp * DCHP + l32 * 4];
        const float a = projT[pp][g0];
        const float b = projT[pp][g1];
        o0.x = fmaf(a, vu4.x, o0.x); o0.y = fmaf(a, vu4.y, o0.y);
        o0.z = fmaf(a, vu4.z, o0.z); o0.w = fmaf(a, vu4.w, o0.w);
        o1.x = fmaf(b, vu4.x, o1.x); o1.y = fmaf(b, vu4.y, o1.y);
        o1.z = fmaf(b, vu4.z, o1.z); o1.w = fmaf(b, vu4.w, o1.w);
    }

    if (MODE == 0) {
        *(float4*)(dst + (size_t)gs[g0] * DDIM + c * DCHP + l32 * 4) = o0;
        *(float4*)(dst + (size_t)gs[g1] * DDIM + c * DCHP + l32 * 4) = o1;
    } else {
        if (g0 < gv) {
            float* op = dst + (size_t)gt[g0] * DDIM + c * DCHP + l32 * 4;
            atomicAdd(op + 0, o0.x); atomicAdd(op + 1, o0.y);
            atomicAdd(op + 2, o0.z); atomicAdd(op + 3, o0.w);
        }
        if (g1 < gv) {
            float* op = dst + (size_t)gt[g1] * DDIM + c * DCHP + l32 * 4;
            atomicAdd(op + 0, o1.x); atomicAdd(op + 1, o1.y);
            atomicAdd(op + 2, o1.z); atomicAdd(op + 3, o1.w);
        }
    }
}

// ---------------------------------------------------------------------------
// K4: out[t] = x[t] + sum_k contrib[slotof[t][k]]  (verbatim-verified)
__global__ __launch_bounds__(BLOCK) void combine_kernel(
    const float* __restrict__ x, const float* __restrict__ contrib,
    const int* __restrict__ slotof, float* __restrict__ out)
{
    __shared__ int sl[TOPK];
    const int t = blockIdx.x, tid = threadIdx.x;
    if (tid < TOPK) sl[tid] = slotof[t * TOPK + tid];
    __syncthreads();
    float4 r = ((const float4*)(x + (size_t)t * DDIM))[tid];
    #pragma unroll
    for (int k = 0; k < TOPK; ++k) {
        const float4 cv = ((const float4*)(contrib + (size_t)sl[k] * DDIM))[tid];
        r.x += cv.x; r.y += cv.y; r.z += cv.z; r.w += cv.w;
    }
    ((float4*)(out + (size_t)t * DDIM))[tid] = r;
}

// ---------------------------------------------------------------------------
extern "C" void kernel_launch(void* const* d_in, const int* in_sizes, int n_in,
                              void* d_out, int out_size, void* d_ws, size_t ws_size,
                              hipStream_t stream) {
    const float* x        = (const float*)d_in[0];
    const float* hasher_w = (const float*)d_in[1];
    const float* keys     = (const float*)d_in[2];
    const float* vd       = (const float*)d_in[3];
    const float* vu       = (const float*)d_in[4];
    const float* scale    = (const float*)d_in[5];
    float* out = (float*)d_out;

    const int ntok = in_sizes[0] / DDIM;        // B*T
    if (ntok <= 0) return;
    const int nent = ntok * TOPK;
    const int maxt = (nent + GT - 1) / GT + NPAT;   // worst-case tile count

    // workspace layout
    char* w = (char*)d_ws;
    const size_t o_offs = 1024;                                   // 257 int
    const size_t o_tki  = 2560;                                   // nent int
    const size_t o_tkw  = o_tki  + (size_t)nent * 4;
    const size_t o_etok = o_tkw  + (size_t)nent * 4;
    const size_t o_ew   = o_etok + (size_t)nent * 4;
    const size_t o_slot = o_ew   + (size_t)nent * 4;
    const size_t o_t2p  = o_slot + (size_t)nent * 4;
    const size_t o_tli  = o_t2p  + (size_t)maxt * 4;
    const size_t o_part = (o_tli + (size_t)maxt * 4 + 255) & ~(size_t)255;
    const size_t partsz = (size_t)NCHP * (size_t)(nent + 1) * PDIM * 4;
    const size_t o_ctb  = (o_part + partsz + 255) & ~(size_t)255;
    const size_t needPart    = o_ctb;                              // atomic path
    const size_t needContrib = o_ctb + (size_t)(nent + 1) * DDIM * 4;

    int*   offs   = (int*)(w + o_offs);
    int*   tki    = (int*)(w + o_tki);
    float* tkw    = (float*)(w + o_tkw);
    int*   etok   = (int*)(w + o_etok);
    float* ew     = (float*)(w + o_ew);
    int*   slotof = (int*)(w + o_slot);
    int*   tile2p = (int*)(w + o_t2p);
    int*   tilei  = (int*)(w + o_tli);
    float* part   = (float*)(w + o_part);
    float* contrib= (float*)(w + o_ctb);

    const int rblocks = (ntok + RTPB - 1) / RTPB;
    hipLaunchKernelGGL(route_kernel, dim3(rblocks), dim3(BLOCK), 0, stream,
                       x, hasher_w, keys, tki, tkw, ntok);
    hipLaunchKernelGGL(scanfill_kernel, dim3(1), dim3(NPAT), 0, stream,
                       tki, tkw, scale, offs, etok, ew, slotof,
                       tile2p, tilei, nent, maxt);
    hipLaunchKernelGGL(proj_kernel, dim3(maxt * NCHP), dim3(BLOCK), 0, stream,
                       x, vd, offs, etok, tile2p, tilei, part, nent);

    if (ws_size >= needContrib) {
        hipLaunchKernelGGL((up_kernel<0>), dim3(maxt * NCHP), dim3(BLOCK), 0, stream,
                           vu, offs, etok, ew, tile2p, tilei, part, contrib, nent);
        hipLaunchKernelGGL(combine_kernel, dim3(ntok), dim3(BLOCK), 0, stream,
                           x, contrib, slotof, out);
    } else if (ws_size >= needPart) {
        hipMemcpyAsync(out, x, (size_t)ntok * DDIM * 4, hipMemcpyDeviceToDevice,
                       stream);
        hipLaunchKernelGGL((up_kernel<1>), dim3(maxt * NCHP), dim3(BLOCK), 0, stream,
                           vu, offs, etok, ew, tile2p, tilei, part, out, nent);
    }
}

// Round 5
// 185.969 us; speedup vs baseline: 2.1006x; 1.1231x over previous
//
#include <hip/hip_runtime.h>
#include <math.h>
#include <float.h>

#define DDIM 1024   // D
#define PDIM 32     // pattern_dim
#define NPAT 256    // n_patterns
#define TOPK 4
#define BLOCK 256
#define GT   16     // tokens per tile
#define DCHP 128    // d-chunk per block (proj & up)
#define NCHP 8      // d-chunks (DDIM/DCHP)
#define RTPB 4      // tokens per route block (one per wave)

// ---------------------------------------------------------------------------
// K0 (R12): routing, one WAVE per token, 4 tokens/block, 512 blocks.
// NEW vs R8: hasher_w staged into LDS per 256-d segment (block-shared, so
// hasher global traffic drops 16x: 1 GB -> 64 MB of L2 reads), and lane 0
// atomically counts this token's top-4 patterns into gcount (replaces the
// serial count pass of the old single-block scanfill).
// The 32 KB hasher buffer aliases the transpose scratch (sequential use).
__global__ __launch_bounds__(BLOCK) void route_kernel(
    const float* __restrict__ x,
    const float* __restrict__ hasher_w,   // [PDIM, DDIM]
    const float* __restrict__ keys,       // [NPAT, PDIM]
    int*   __restrict__ tki,              // [ntok, TOPK]
    float* __restrict__ tkw,              // [ntok, TOPK]
    int*   __restrict__ gcount,           // [NPAT], pre-zeroed
    int ntok)
{
    // shared: max(hasher seg 32*256 = 8192 floats, P_s 4*64*33 = 8448 floats)
    __shared__ float shmem[RTPB * 64 * 33];   // 33.8 KB, dual-purpose
    __shared__ float h_s[RTPB][32];

    const int tid  = threadIdx.x;
    const int wv   = tid >> 6;            // wave 0..3 = local token
    const int lane = tid & 63;
    const int traw = blockIdx.x * RTPB + wv;
    const int tok  = min(traw, ntok - 1); // clamp (dup-write benign for tki/tkw)

    // ---- x row into registers (coalesced float4)
    const float4* xrow = (const float4*)(x + (size_t)tok * DDIM);
    float4 xr[4];
    #pragma unroll
    for (int i = 0; i < 4; ++i) xr[i] = xrow[i * 64 + lane];

    // ---- h: accumulate over four 256-d segments, hasher staged in LDS
    float part[PDIM];
    #pragma unroll
    for (int pp = 0; pp < PDIM; ++pp) part[pp] = 0.f;

    float* hs = shmem;                    // [32][256] floats per segment
    for (int i = 0; i < 4; ++i) {
        // stage hasher[:, i*256 .. i*256+255]: 2048 float4, 8 per thread
        #pragma unroll
        for (int k = 0; k < 8; ++k) {
            const int q  = k * 256 + tid;
            const int pp = q >> 6, fi = q & 63;
            ((float4*)hs)[q] =
                *(const float4*)(hasher_w + (size_t)pp * DDIM + i * 256 + fi * 4);
        }
        __syncthreads();
        #pragma unroll
        for (int pp = 0; pp < PDIM; ++pp) {
            const float4 w4 = *(const float4*)&hs[pp * 256 + lane * 4];
            part[pp] = fmaf(xr[i].x, w4.x, part[pp]);
            part[pp] = fmaf(xr[i].y, w4.y, part[pp]);
            part[pp] = fmaf(xr[i].z, w4.z, part[pp]);
            part[pp] = fmaf(xr[i].w, w4.w, part[pp]);
        }
        __syncthreads();                  // hs reads done before next stage / P writes
    }

    // ---- transpose-reduce: P[l][pp] -> h[pp]  (P aliases hs region)
    float* P = shmem + wv * (64 * 33);
    #pragma unroll
    for (int pp = 0; pp < PDIM; ++pp) P[lane * 33 + pp] = part[pp];
    __syncthreads();

    {
        const int pp = lane & 31, half = lane >> 5;
        float hsum = 0.f;
        #pragma unroll 8
        for (int i = 0; i < 32; ++i)
            hsum += P[(half * 32 + i) * 33 + pp];
        hsum += __shfl_xor(hsum, 32, 64);
        if (half == 0) h_s[wv][pp] = hsum;
    }
    __syncthreads();

    // ---- sim + top4 + softmax (verbatim logic, validated)
    float4 h4[8];
    #pragma unroll
    for (int i = 0; i < 8; ++i) h4[i] = *(const float4*)&h_s[wv][i * 4];

    float sc0, sc1, sc2, sc3;
    {
        float sv[4];
        #pragma unroll
        for (int c = 0; c < 4; ++c) {
            const float4* kr = (const float4*)(keys + (size_t)(c * 64 + lane) * PDIM);
            float a = 0.f;
            #pragma unroll
            for (int i = 0; i < 8; ++i) {
                const float4 k4 = kr[i];
                a = fmaf(k4.x, h4[i].x, a); a = fmaf(k4.y, h4[i].y, a);
                a = fmaf(k4.z, h4[i].z, a); a = fmaf(k4.w, h4[i].w, a);
            }
            sv[c] = a;
        }
        sc0 = sv[0]; sc1 = sv[1]; sc2 = sv[2]; sc3 = sv[3];
    }

    float wval[TOPK]; int widx[TOPK];
    #pragma unroll
    for (int r = 0; r < TOPK; ++r) {
        float bv = sc0; int bc = 0;
        if (sc1 > bv) { bv = sc1; bc = 1; }
        if (sc2 > bv) { bv = sc2; bc = 2; }
        if (sc3 > bv) { bv = sc3; bc = 3; }
        int bidx = bc * 64 + lane;
        #pragma unroll
        for (int off = 1; off < 64; off <<= 1) {
            const float ov = __shfl_xor(bv, off, 64);
            const int   oi = __shfl_xor(bidx, off, 64);
            if (ov > bv || (ov == bv && oi < bidx)) { bv = ov; bidx = oi; }
        }
        wval[r] = bv; widx[r] = bidx;
        if ((bidx & 63) == lane) {
            const int c = bidx >> 6;
            if (c == 0) sc0 = -FLT_MAX;
            else if (c == 1) sc1 = -FLT_MAX;
            else if (c == 2) sc2 = -FLT_MAX;
            else sc3 = -FLT_MAX;
        }
    }

    if (lane == 0 && traw < ntok) {
        float m = wval[0];
        #pragma unroll
        for (int k = 1; k < TOPK; ++k) m = fmaxf(m, wval[k]);
        float s = 0.f, e[TOPK];
        #pragma unroll
        for (int k = 0; k < TOPK; ++k) { e[k] = expf(wval[k] - m); s += e[k]; }
        #pragma unroll
        for (int k = 0; k < TOPK; ++k) {
            tki[tok * TOPK + k] = widx[k];
            tkw[tok * TOPK + k] = e[k] / s;
            atomicAdd(&gcount[widx[k]], 1);
        }
    }
}

// ---------------------------------------------------------------------------
// K1a (R12): single small block — scan gcount -> offs, init gcur, and build
// the tile list. ~256-wide work only, a few us.
__global__ __launch_bounds__(NPAT) void scan_kernel(
    const int* __restrict__ gcount,
    int* __restrict__ offs,
    int* __restrict__ gcur,
    int* __restrict__ tile2p, int* __restrict__ tilei,
    int maxt)
{
    __shared__ int s[NPAT];
    const int tid = threadIdx.x;

    const int v = gcount[tid];
    s[tid] = v;
    __syncthreads();
    for (int off = 1; off < NPAT; off <<= 1) {
        int t = 0;
        if (tid >= off) t = s[tid - off];
        __syncthreads();
        s[tid] += t;
        __syncthreads();
    }
    const int incl = s[tid];
    offs[tid + 1] = incl;
    if (tid == 0) offs[0] = 0;
    gcur[tid] = incl - v;                 // exclusive offset for fill

    // tile decomposition: scan of ceil(v/GT)
    const int tc = (v + GT - 1) / GT;
    __syncthreads();
    s[tid] = tc;
    __syncthreads();
    for (int off = 1; off < NPAT; off <<= 1) {
        int t = 0;
        if (tid >= off) t = s[tid - off];
        __syncthreads();
        s[tid] += t;
        __syncthreads();
    }
    const int toff = s[tid] - tc;
    for (int i = tid; i < maxt; i += NPAT) tile2p[i] = -1;
    __syncthreads();
    for (int i = 0; i < tc; ++i) { tile2p[toff + i] = tid; tilei[toff + i] = i; }
}

// ---------------------------------------------------------------------------
// K1b (R12): parallel CSR fill — one entry per thread, global atomic slot.
__global__ __launch_bounds__(BLOCK) void fill_kernel(
    const int* __restrict__ tki, const float* __restrict__ tkw,
    const float* __restrict__ scale_p,
    int* __restrict__ gcur,
    int* __restrict__ etok, float* __restrict__ ew, int* __restrict__ slotof,
    int nent)
{
    const int e = blockIdx.x * BLOCK + threadIdx.x;
    if (e >= nent) return;
    const int p = tki[e];
    const int slot = atomicAdd(&gcur[p], 1);
    etok[slot] = e >> 2;
    ew[slot]   = tkw[e] * scale_p[0];
    slotof[e]  = slot;
}

// ---------------------------------------------------------------------------
// K2 (R11, verbatim-validated): down-projection, one tile x one 128-d chunk.
__global__ __launch_bounds__(BLOCK, 6) void proj_kernel(
    const float* __restrict__ x,
    const float* __restrict__ vd,          // [NPAT, DDIM, PDIM]
    const int* __restrict__ offs,
    const int* __restrict__ etok,
    const int* __restrict__ tile2p,
    const int* __restrict__ tilei,
    float* __restrict__ part,              // [NCHP][nent+1][PDIM]
    int nent)
{
    __shared__ float vd_s[DCHP * PDIM];    // 16 KB
    __shared__ float x_s[GT * DCHP];       // 8 KB
    __shared__ int   gt[GT];
    __shared__ int   gs[GT];

    const int tb  = blockIdx.x >> 3;
    const int c   = blockIdx.x & 7;
    const int p   = tile2p[tb];
    if (p < 0) return;
    const int tid = threadIdx.x;
    const int off0 = offs[p] + tilei[tb] * GT;
    const int gv   = min(GT, offs[p + 1] - off0);

    const float* vdp = vd + (size_t)p * DDIM * PDIM + (size_t)c * DCHP * PDIM;
    #pragma unroll
    for (int k = 0; k < 4; ++k)
        ((float4*)vd_s)[k * 256 + tid] = ((const float4*)vdp)[k * 256 + tid];

    if (tid < GT) {
        if (tid < gv) { gt[tid] = etok[off0 + tid]; gs[tid] = off0 + tid; }
        else          { gt[tid] = etok[off0];       gs[tid] = nent; }
    }
    __syncthreads();

    #pragma unroll
    for (int k = 0; k < 2; ++k) {
        const int q  = k * 256 + tid;
        const int g  = q >> 5, fi = q & 31;
        ((float4*)x_s)[g * 32 + fi] =
            *(const float4*)(x + (size_t)gt[g] * DDIM + c * DCHP + fi * 4);
    }
    __syncthreads();

    const int lane = tid & 63;
    const int wv   = tid >> 6;
    const int pp4  = lane & 7;
    const int seg  = lane >> 3;

    float4 acc[4];
    #pragma unroll
    for (int j = 0; j < 4; ++j) acc[j] = make_float4(0.f, 0.f, 0.f, 0.f);

    #pragma unroll
    for (int i4 = 0; i4 < 4; ++i4) {
        const int d0 = seg * 16 + i4 * 4;
        const float4 v0 = *(const float4*)&vd_s[(d0 + 0) * PDIM + pp4 * 4];
        const float4 v1 = *(const float4*)&vd_s[(d0 + 1) * PDIM + pp4 * 4];
        const float4 v2 = *(const float4*)&vd_s[(d0 + 2) * PDIM + pp4 * 4];
        const float4 v3 = *(const float4*)&vd_s[(d0 + 3) * PDIM + pp4 * 4];
        #pragma unroll
        for (int j = 0; j < 4; ++j) {
            const float4 xg = *(const float4*)&x_s[(wv * 4 + j) * DCHP + d0];
            acc[j].x = fmaf(xg.x, v0.x, acc[j].x);
            acc[j].y = fmaf(xg.x, v0.y, acc[j].y);
            acc[j].z = fmaf(xg.x, v0.z, acc[j].z);
            acc[j].w = fmaf(xg.x, v0.w, acc[j].w);
            acc[j].x = fmaf(xg.y, v1.x, acc[j].x);
            acc[j].y = fmaf(xg.y, v1.y, acc[j].y);
            acc[j].z = fmaf(xg.y, v1.z, acc[j].z);
            acc[j].w = fmaf(xg.y, v1.w, acc[j].w);
            acc[j].x = fmaf(xg.z, v2.x, acc[j].x);
            acc[j].y = fmaf(xg.z, v2.y, acc[j].y);
            acc[j].z = fmaf(xg.z, v2.z, acc[j].z);
            acc[j].w = fmaf(xg.z, v2.w, acc[j].w);
            acc[j].x = fmaf(xg.w, v3.x, acc[j].x);
            acc[j].y = fmaf(xg.w, v3.y, acc[j].y);
            acc[j].z = fmaf(xg.w, v3.z, acc[j].z);
            acc[j].w = fmaf(xg.w, v3.w, acc[j].w);
        }
    }

    #pragma unroll
    for (int j = 0; j < 4; ++j) {
        #pragma unroll
        for (int off = 8; off <= 32; off <<= 1) {
            acc[j].x += __shfl_xor(acc[j].x, off, 64);
            acc[j].y += __shfl_xor(acc[j].y, off, 64);
            acc[j].z += __shfl_xor(acc[j].z, off, 64);
            acc[j].w += __shfl_xor(acc[j].w, off, 64);
        }
    }

    float* partc = part + (size_t)c * (size_t)(nent + 1) * PDIM;
    if ((lane & 0x38) == 0) {
        #pragma unroll
        for (int j = 0; j < 4; ++j)
            *(float4*)&partc[(size_t)gs[wv * 4 + j] * PDIM + pp4 * 4] = acc[j];
    }
}

// ---------------------------------------------------------------------------
// K3 (R11, verbatim-validated): up-projection, one tile x one 128-d chunk.
template <int MODE>
__global__ __launch_bounds__(BLOCK, 6) void up_kernel(
    const float* __restrict__ vu,          // [NPAT, PDIM, DDIM]
    const int* __restrict__ offs,
    const int* __restrict__ etok,
    const float* __restrict__ ew,
    const int* __restrict__ tile2p,
    const int* __restrict__ tilei,
    const float* __restrict__ part,        // [NCHP][nent+1][PDIM]
    float* __restrict__ dst,               // contrib (MODE 0) or out (MODE 1)
    int nent)
{
    __shared__ float vu_s[PDIM * DCHP];    // 16 KB
    __shared__ float projT[PDIM][20];
    __shared__ int   gt[GT];
    __shared__ float gw[GT];
    __shared__ int   gs[GT];

    const int tb  = blockIdx.x >> 3;
    const int c   = blockIdx.x & 7;
    const int p   = tile2p[tb];
    if (p < 0) return;
    const int tid = threadIdx.x;
    const int off0 = offs[p] + tilei[tb] * GT;
    const int gv   = min(GT, offs[p + 1] - off0);

    const size_t PS = (size_t)(nent + 1) * PDIM;

    const float* vup = vu + (size_t)p * PDIM * DDIM + (size_t)c * DCHP;
    #pragma unroll
    for (int k = 0; k < 4; ++k) {
        const int q  = k * 256 + tid;
        const int pp = q >> 5, fi = q & 31;
        *(float4*)&vu_s[pp * DCHP + fi * 4] =
            *(const float4*)(vup + (size_t)pp * DDIM + fi * 4);
    }
    if (tid < GT) {
        if (tid < gv) {
            gt[tid] = etok[off0 + tid];
            gw[tid] = ew[off0 + tid];
            gs[tid] = off0 + tid;
        } else {
            gt[tid] = etok[off0]; gw[tid] = 0.f; gs[tid] = nent;
        }
    }
    __syncthreads();

    #pragma unroll
    for (int r = 0; r < 2; ++r) {
        const int idx = tid + r * BLOCK;
        const int g = idx >> 5, pp = idx & 31;
        const size_t row = (size_t)gs[g] * PDIM + pp;
        float s = 0.f;
        #pragma unroll
        for (int i = 0; i < NCHP; ++i) s += part[i * PS + row];
        const float pj = s / (1.f + expf(-s));
        projT[pp][g] = pj * gw[g];
    }
    __syncthreads();

    const int tg  = tid >> 5;
    const int l32 = tid & 31;
    const int g0 = tg * 2, g1 = tg * 2 + 1;

    float4 o0 = make_float4(0.f, 0.f, 0.f, 0.f);
    float4 o1 = o0;
    #pragma unroll
    for (int pp = 0; pp < PDIM; ++pp) {
        const float4 vu4 = *(const float4*)&vu_s[pp * DCHP + l32 * 4];
        const float a = projT[pp][g0];
        const float b = projT[pp][g1];
        o0.x = fmaf(a, vu4.x, o0.x); o0.y = fmaf(a, vu4.y, o0.y);
        o0.z = fmaf(a, vu4.z, o0.z); o0.w = fmaf(a, vu4.w, o0.w);
        o1.x = fmaf(b, vu4.x, o1.x); o1.y = fmaf(b, vu4.y, o1.y);
        o1.z = fmaf(b, vu4.z, o1.z); o1.w = fmaf(b, vu4.w, o1.w);
    }

    if (MODE == 0) {
        *(float4*)(dst + (size_t)gs[g0] * DDIM + c * DCHP + l32 * 4) = o0;
        *(float4*)(dst + (size_t)gs[g1] * DDIM + c * DCHP + l32 * 4) = o1;
    } else {
        if (g0 < gv) {
            float* op = dst + (size_t)gt[g0] * DDIM + c * DCHP + l32 * 4;
            atomicAdd(op + 0, o0.x); atomicAdd(op + 1, o0.y);
            atomicAdd(op + 2, o0.z); atomicAdd(op + 3, o0.w);
        }
        if (g1 < gv) {
            float* op = dst + (size_t)gt[g1] * DDIM + c * DCHP + l32 * 4;
            atomicAdd(op + 0, o1.x); atomicAdd(op + 1, o1.y);
            atomicAdd(op + 2, o1.z); atomicAdd(op + 3, o1.w);
        }
    }
}

// ---------------------------------------------------------------------------
// K4: out[t] = x[t] + sum_k contrib[slotof[t][k]]  (verbatim-verified)
__global__ __launch_bounds__(BLOCK) void combine_kernel(
    const float* __restrict__ x, const float* __restrict__ contrib,
    const int* __restrict__ slotof, float* __restrict__ out)
{
    __shared__ int sl[TOPK];
    const int t = blockIdx.x, tid = threadIdx.x;
    if (tid < TOPK) sl[tid] = slotof[t * TOPK + tid];
    __syncthreads();
    float4 r = ((const float4*)(x + (size_t)t * DDIM))[tid];
    #pragma unroll
    for (int k = 0; k < TOPK; ++k) {
        const float4 cv = ((const float4*)(contrib + (size_t)sl[k] * DDIM))[tid];
        r.x += cv.x; r.y += cv.y; r.z += cv.z; r.w += cv.w;
    }
    ((float4*)(out + (size_t)t * DDIM))[tid] = r;
}

// ---------------------------------------------------------------------------
extern "C" void kernel_launch(void* const* d_in, const int* in_sizes, int n_in,
                              void* d_out, int out_size, void* d_ws, size_t ws_size,
                              hipStream_t stream) {
    const float* x        = (const float*)d_in[0];
    const float* hasher_w = (const float*)d_in[1];
    const float* keys     = (const float*)d_in[2];
    const float* vd       = (const float*)d_in[3];
    const float* vu       = (const float*)d_in[4];
    const float* scale    = (const float*)d_in[5];
    float* out = (float*)d_out;

    const int ntok = in_sizes[0] / DDIM;        // B*T
    if (ntok <= 0) return;
    const int nent = ntok * TOPK;
    const int maxt = (nent + GT - 1) / GT + NPAT;   // worst-case tile count

    // workspace layout
    char* w = (char*)d_ws;
    const size_t o_gcnt = 0;                                      // 256 int
    const size_t o_gcur = 1024;                                   // 256 int
    const size_t o_offs = 2048;                                   // 257 int
    const size_t o_tki  = 4096;                                   // nent int
    const size_t o_tkw  = o_tki  + (size_t)nent * 4;
    const size_t o_etok = o_tkw  + (size_t)nent * 4;
    const size_t o_ew   = o_etok + (size_t)nent * 4;
    const size_t o_slot = o_ew   + (size_t)nent * 4;
    const size_t o_t2p  = o_slot + (size_t)nent * 4;
    const size_t o_tli  = o_t2p  + (size_t)maxt * 4;
    const size_t o_part = (o_tli + (size_t)maxt * 4 + 255) & ~(size_t)255;
    const size_t partsz = (size_t)NCHP * (size_t)(nent + 1) * PDIM * 4;
    const size_t o_ctb  = (o_part + partsz + 255) & ~(size_t)255;
    const size_t needPart    = o_ctb;                              // atomic path
    const size_t needContrib = o_ctb + (size_t)(nent + 1) * DDIM * 4;

    int*   gcount = (int*)(w + o_gcnt);
    int*   gcur   = (int*)(w + o_gcur);
    int*   offs   = (int*)(w + o_offs);
    int*   tki    = (int*)(w + o_tki);
    float* tkw    = (float*)(w + o_tkw);
    int*   etok   = (int*)(w + o_etok);
    float* ew     = (float*)(w + o_ew);
    int*   slotof = (int*)(w + o_slot);
    int*   tile2p = (int*)(w + o_t2p);
    int*   tilei  = (int*)(w + o_tli);
    float* part   = (float*)(w + o_part);
    float* contrib= (float*)(w + o_ctb);

    hipMemsetAsync(gcount, 0, NPAT * sizeof(int), stream);

    const int rblocks = (ntok + RTPB - 1) / RTPB;
    hipLaunchKernelGGL(route_kernel, dim3(rblocks), dim3(BLOCK), 0, stream,
                       x, hasher_w, keys, tki, tkw, gcount, ntok);
    hipLaunchKernelGGL(scan_kernel, dim3(1), dim3(NPAT), 0, stream,
                       gcount, offs, gcur, tile2p, tilei, maxt);
    hipLaunchKernelGGL(fill_kernel, dim3((nent + BLOCK - 1) / BLOCK), dim3(BLOCK),
                       0, stream, tki, tkw, scale, gcur, etok, ew, slotof, nent);
    hipLaunchKernelGGL(proj_kernel, dim3(maxt * NCHP), dim3(BLOCK), 0, stream,
                       x, vd, offs, etok, tile2p, tilei, part, nent);

    if (ws_size >= needContrib) {
        hipLaunchKernelGGL((up_kernel<0>), dim3(maxt * NCHP), dim3(BLOCK), 0, stream,
                           vu, offs, etok, ew, tile2p, tilei, part, contrib, nent);
        hipLaunchKernelGGL(combine_kernel, dim3(ntok), dim3(BLOCK), 0, stream,
                           x, contrib, slotof, out);
    } else if (ws_size >= needPart) {
        hipMemcpyAsync(out, x, (size_t)ntok * DDIM * 4, hipMemcpyDeviceToDevice,
                       stream);
        hipLaunchKernelGGL((up_kernel<1>), dim3(maxt * NCHP), dim3(BLOCK), 0, stream,
                           vu, offs, etok, ew, tile2p, tilei, part, out, nent);
    }
}